// Round 2
// baseline (273.591 us; speedup 1.0000x reference)
//
#include <hip/hip_runtime.h>
#include <stdint.h>

// Pipeline: 3-layer binary network, all layers as XNOR-popcount on bit-packed vectors.
// ws layout (bytes):
//   X1p : 65536*32 u32 @ 0          (8 MB)   packed layer-1 input bits per pixel
//   cA  : 256*1024 s8  @ 8388608             (L0 h-count minus thr0)
//   cB  : 256*1024 u8  @ 8650752             (L0 w-count)
//   M1p : 1024*32 u32  @ 8912896             mask1 columns bit-packed
//   M2p : 24*32  u32   @ 9043968             mask2 columns bit-packed

#define WS_CA  8388608
#define WS_CB  8650752
#define WS_M1  8912896
#define WS_M2  9043968

// ---- mask upload-format sniffing (bool arrays may arrive as u8, i32, or f32) ----
// mode: 0 = u8 (1 byte/elem), 1 = i32 (4 bytes/elem), 2 = f32 (0.0/1.0)
__device__ inline int detect_mode(const unsigned char* p) {
  unsigned nonalign = 0;
  for (int i = 0; i < 64; i++)
    if (i & 3) nonalign |= p[i];
  if (nonalign == 0) return 1;                 // int32 0/1: bytes 1..3 of each elem zero
  bool f32ok = true;
  for (int e = 0; e < 16; e++) {
    const unsigned char* q = p + 4 * e;
    bool one  = (q[0] == 0 && q[1] == 0 && q[2] == 0x80 && q[3] == 0x3F);
    bool zero = (q[0] == 0 && q[1] == 0 && q[2] == 0 && q[3] == 0);
    if (!(one || zero)) { f32ok = false; break; }
  }
  return f32ok ? 2 : 0;
}

__device__ inline int maskbit(const unsigned char* p, int idx, int mode) {
  if (mode == 1) return ((const int*)p)[idx] & 1;
  if (mode == 2) return ((const float*)p)[idx] != 0.0f;
  return p[idx] & 1;
}

__global__ __launch_bounds__(256) void prep_kernel(
    const unsigned char* __restrict__ mask0, const int* __restrict__ thr0,
    const unsigned char* __restrict__ mask1, const unsigned char* __restrict__ mask2,
    signed char* __restrict__ cA, unsigned char* __restrict__ cB,
    unsigned* __restrict__ M1p, unsigned* __restrict__ M2p) {
  int mode = detect_mode(mask1);   // all masks share one upload convention
  int gid = blockIdx.x * 256 + threadIdx.x;
  if (gid < 524288) {              // cA / cB tables
    int which = gid >> 18;         // 0 = cA (h-bits), 1 = cB (w-bits)
    int idx = gid & 262143;
    int hw = idx >> 10;
    int o  = idx & 1023;
    int base = which ? 8 : 0;
    int cnt = 0;
#pragma unroll
    for (int i = 0; i < 8; i++) {
      int xb = (hw >> (7 - i)) & 1;                     // MSB-first bits
      int mb = maskbit(mask0, (base + i) * 1024 + o, mode);
      cnt += (xb == mb);
    }
    if (which) cB[idx] = (unsigned char)cnt;
    else       cA[idx] = (signed char)(cnt - thr0[o]);  // fold threshold in
    return;
  }
  int g2 = gid - 524288;
  if (g2 < 32768) {                // pack mask1 column bits: M1p[o][kw]
    int kw = g2 >> 10, o = g2 & 1023;
    unsigned wv = 0;
#pragma unroll
    for (int b = 0; b < 32; b++)
      wv |= (unsigned)maskbit(mask1, (kw * 32 + b) * 1024 + o, mode) << b;  // LSB-first
    M1p[o * 32 + kw] = wv;
    return;
  }
  int g3 = g2 - 32768;
  if (g3 < 768) {                  // pack mask2: M2p[o][kw]
    int kw = g3 / 24, o = g3 % 24;
    unsigned wv = 0;
    for (int b = 0; b < 32; b++)
      wv |= (unsigned)maskbit(mask2, (kw * 32 + b) * 24 + o, mode) << b;
    M2p[o * 32 + kw] = wv;
  }
}

// Layer-0 evaluate + bit-pack: X1p[n][kw], bit b of word kw <-> feature kw*32+b
__global__ __launch_bounds__(256) void pack_x1(
    const signed char* __restrict__ cA, const unsigned char* __restrict__ cB,
    unsigned* __restrict__ X1p) {
  int t = threadIdx.x;
  int gw = (blockIdx.x * 256 + t) >> 6;  // global wave id: n*4+q
  int lane = t & 63;
  int n = gw >> 2;
  int q = gw & 3;
  int h = n >> 8, w = n & 255;
  const signed char*   ca = cA + h * 1024;
  const unsigned char* cb = cB + w * 1024;
#pragma unroll
  for (int j = 0; j < 4; j++) {
    int o = q * 256 + j * 64 + lane;
    bool bit = ((int)ca[o] + (int)cb[o]) > 0;          // cA+cB > thr0
    unsigned long long bal = __ballot(bit);
    if (lane == 0) {
      uint2 v; v.x = (unsigned)bal; v.y = (unsigned)(bal >> 32);
      *reinterpret_cast<uint2*>(&X1p[n * 32 + q * 8 + 2 * j]) = v;
    }
  }
}

// Main: L1 popcount-GEMM (128px x 1024out per block) + fused L2 + epilogue.
// LDS word-swizzle: word index k ^= (row&7)<<2 keeps uint4 groups intact and
// spreads the 128B row stride across banks (T2-style fix).
__global__ __launch_bounds__(256) void main_kernel(
    const unsigned* __restrict__ X1p, const unsigned* __restrict__ M1p,
    const unsigned* __restrict__ M2p, const int* __restrict__ thr1,
    const int* __restrict__ thr2, const float* __restrict__ image,
    float* __restrict__ out) {
  __shared__ unsigned lx[128 * 32];
  __shared__ unsigned lm[128 * 32];
  __shared__ unsigned lx2[128 * 32];
  __shared__ unsigned lm2[24 * 32];
  __shared__ unsigned char bitb[128 * 24];
  int t = threadIdx.x;
  int n0 = blockIdx.x << 7;

  // stage X tile (128 rows x 32 words), swizzled
#pragma unroll
  for (int i = 0; i < 4; i++) {
    int idx = t + i * 256;           // uint4 index within tile
    int row = idx >> 3;
    int k4 = (idx & 7) << 2;
    uint4 v = reinterpret_cast<const uint4*>(X1p)[n0 * 8 + idx];
    int kk = k4 ^ ((row & 7) << 2);
    *reinterpret_cast<uint4*>(&lx[row * 32 + kk]) = v;
  }
  if (t < 768) lm2[t] = M2p[t];

  int oc_t = t & 15;                 // output-thread 0..15
  int pr_t = t >> 4;                 // pixel-thread 0..15
  int pgrp = (t >> 4) & 3;           // pixel group within wave

  for (int oc = 0; oc < 8; oc++) {
    __syncthreads();                 // protect lm from previous iteration
#pragma unroll
    for (int i = 0; i < 4; i++) {
      int idx = t + i * 256;
      int row = idx >> 3;
      int k4 = (idx & 7) << 2;
      uint4 v = reinterpret_cast<const uint4*>(M1p)[oc * 1024 + idx];
      int kk = k4 ^ ((row & 7) << 2);
      *reinterpret_cast<uint4*>(&lm[row * 32 + kk]) = v;
    }
    __syncthreads();

    unsigned acc[8][8];
#pragma unroll
    for (int i = 0; i < 8; i++)
#pragma unroll
      for (int j = 0; j < 8; j++) acc[i][j] = 0;

#pragma unroll
    for (int k4 = 0; k4 < 32; k4 += 4) {
      uint4 xv[8], mv[8];
#pragma unroll
      for (int i = 0; i < 8; i++) {
        int row = pr_t + (i << 4);
        xv[i] = *reinterpret_cast<const uint4*>(&lx[row * 32 + (k4 ^ ((row & 7) << 2))]);
        int orow = oc_t + (i << 4);
        mv[i] = *reinterpret_cast<const uint4*>(&lm[orow * 32 + (k4 ^ ((orow & 7) << 2))]);
      }
#pragma unroll
      for (int i = 0; i < 8; i++)
#pragma unroll
        for (int j = 0; j < 8; j++) {
          acc[i][j] += __popc(xv[i].x ^ mv[j].x);
          acc[i][j] += __popc(xv[i].y ^ mv[j].y);
          acc[i][j] += __popc(xv[i].z ^ mv[j].z);
          acc[i][j] += __popc(xv[i].w ^ mv[j].w);
        }
    }

    // threshold + ballot-pack x2 bits into lx2
    int limv[8];
#pragma unroll
    for (int j = 0; j < 8; j++)
      limv[j] = 1024 - thr1[(oc << 7) + (j << 4) + oc_t];
#pragma unroll
    for (int i = 0; i < 8; i++) {
      unsigned wacc[4] = {0, 0, 0, 0};
#pragma unroll
      for (int j = 0; j < 8; j++) {
        bool bit = ((int)acc[i][j]) < limv[j];         // match=1024-acc > thr1
        unsigned long long bal = __ballot(bit);
        unsigned hw16 = (unsigned)(bal >> (pgrp << 4)) & 0xFFFFu;
        wacc[j >> 1] |= hw16 << ((j & 1) << 4);
      }
      if (oc_t == 0) {
        int p = pr_t + (i << 4);
#pragma unroll
        for (int wd = 0; wd < 4; wd++)
          lx2[p * 32 + (oc << 2) + wd] = wacc[wd];
      }
    }
  }
  __syncthreads();

  // layer 2: 128 px x 24 outputs
  for (int r = 0; r < 12; r++) {
    int item = t + (r << 8);         // 0..3071
    int p = item & 127;
    int o = item >> 7;               // 0..23
    unsigned acc2 = 0;
#pragma unroll
    for (int k = 0; k < 32; k++)
      acc2 += __popc(lx2[p * 32 + k] ^ lm2[o * 32 + k]);
    bitb[p * 24 + o] = (unsigned char)(((int)(1024u - acc2)) > thr2[o]);
  }
  __syncthreads();

  // epilogue: bits -> int (MSB-first), minus image; harness reads d_out as f32
  if (t < 128) {
    int n = n0 + t;
#pragma unroll
    for (int c = 0; c < 3; c++) {
      int val = 0;
#pragma unroll
      for (int bb = 0; bb < 8; bb++)
        val |= ((int)bitb[t * 24 + c * 8 + bb]) << (7 - bb);
      out[c * 65536 + n] = (float)val;
      float img = image[c * 65536 + n];
      out[196608 + c * 65536 + n] = (float)val - img;
    }
  }
}

extern "C" void kernel_launch(void* const* d_in, const int* in_sizes, int n_in,
                              void* d_out, int out_size, void* d_ws, size_t ws_size,
                              hipStream_t stream) {
  const float*         image = (const float*)d_in[0];
  const unsigned char* mask0 = (const unsigned char*)d_in[1];
  const int*           thr0  = (const int*)d_in[2];
  const unsigned char* mask1 = (const unsigned char*)d_in[3];
  const int*           thr1  = (const int*)d_in[4];
  const unsigned char* mask2 = (const unsigned char*)d_in[5];
  const int*           thr2  = (const int*)d_in[6];
  char* ws = (char*)d_ws;
  unsigned*      X1p = (unsigned*)(ws);
  signed char*   cA  = (signed char*)(ws + WS_CA);
  unsigned char* cB  = (unsigned char*)(ws + WS_CB);
  unsigned*      M1p = (unsigned*)(ws + WS_M1);
  unsigned*      M2p = (unsigned*)(ws + WS_M2);
  float* out = (float*)d_out;

  hipLaunchKernelGGL(prep_kernel, dim3(2179), dim3(256), 0, stream,
                     mask0, thr0, mask1, mask2, cA, cB, M1p, M2p);
  hipLaunchKernelGGL(pack_x1, dim3(65536), dim3(256), 0, stream, cA, cB, X1p);
  hipLaunchKernelGGL(main_kernel, dim3(512), dim3(256), 0, stream,
                     X1p, M1p, M2p, thr1, thr2, image, out);
}